// Round 2
// baseline (1377.496 us; speedup 1.0000x reference)
//
#include <hip/hip_runtime.h>
#include <stdint.h>

#define N_TOK 8192
#define C_DIM 1024
#define H_DIM 3072
#define N_EXP 8
#define N_ASSIGN (N_TOK * 2)

typedef __attribute__((ext_vector_type(8))) short short8;
typedef __attribute__((ext_vector_type(4))) float f32x4;

__device__ __forceinline__ unsigned short f2bf(float f) {
    union { float f; uint32_t u; } v; v.f = f;
    uint32_t r = (v.u + 0x7FFFu + ((v.u >> 16) & 1u)) >> 16;
    return (unsigned short)r;
}

#define GLDS16(SRC, DST) __builtin_amdgcn_global_load_lds( \
    (const __attribute__((address_space(1))) void*)(SRC),  \
    (__attribute__((address_space(3))) void*)(DST), 16, 0, 0)

// ---------------- transpose + fp32->bf16 convert: out[col][row] = in[row][col], per expert (grid.z)
__global__ void transpose_bf16_kernel(const float* __restrict__ in, unsigned short* __restrict__ out,
                                      int rows, int cols) {
    __shared__ float tile[32][33];
    int e = blockIdx.z;
    const float* ip = in + (size_t)e * rows * cols;
    unsigned short* op = out + (size_t)e * rows * cols;
    int col0 = blockIdx.x * 32;
    int row0 = blockIdx.y * 32;
    int tx = threadIdx.x, ty = threadIdx.y;
    tile[ty][tx] = ip[(size_t)(row0 + ty) * cols + col0 + tx];
    __syncthreads();
    op[(size_t)(col0 + ty) * rows + row0 + tx] = f2bf(tile[tx][ty]);
}

// ---------------- router: logits = x @ Wr, softmax, top-2 (lowest-index ties), renorm; pi/cnt stats
__global__ __launch_bounds__(256) void router_kernel(const float* __restrict__ x, const float* __restrict__ Wr,
                                                     int2* __restrict__ idx2, float2* __restrict__ wgt2,
                                                     float* __restrict__ piAcc, int* __restrict__ cntAcc) {
    __shared__ float s_pi[8];
    __shared__ int s_cnt[8];
    int t = threadIdx.x;
    if (t < 8) { s_pi[t] = 0.f; s_cnt[t] = 0; }
    __syncthreads();
    int lane = t & 63;
    int wid = t >> 6;
    int gwv = blockIdx.x * 4 + wid;
    int nw = gridDim.x * 4;
    for (int n = gwv; n < N_TOK; n += nw) {
        float acc[8];
#pragma unroll
        for (int e = 0; e < 8; e++) acc[e] = 0.f;
        const float* xr = x + (size_t)n * C_DIM;
#pragma unroll
        for (int j = 0; j < 16; j++) {
            int k = lane + 64 * j;
            float xv = xr[k];
            const float4* wr4 = (const float4*)(Wr + (size_t)k * 8);
            float4 a = wr4[0], b = wr4[1];
            acc[0] += xv * a.x; acc[1] += xv * a.y; acc[2] += xv * a.z; acc[3] += xv * a.w;
            acc[4] += xv * b.x; acc[5] += xv * b.y; acc[6] += xv * b.z; acc[7] += xv * b.w;
        }
#pragma unroll
        for (int off = 1; off < 64; off <<= 1) {
#pragma unroll
            for (int e = 0; e < 8; e++) acc[e] += __shfl_xor(acc[e], off, 64);
        }
        float m = acc[0];
#pragma unroll
        for (int e = 1; e < 8; e++) m = fmaxf(m, acc[e]);
        float p[8]; float s = 0.f;
#pragma unroll
        for (int e = 0; e < 8; e++) { p[e] = __expf(acc[e] - m); s += p[e]; }
        float inv = 1.f / s;
#pragma unroll
        for (int e = 0; e < 8; e++) p[e] *= inv;
        int i0 = 0; float l0 = acc[0];
#pragma unroll
        for (int e = 1; e < 8; e++) if (acc[e] > l0) { l0 = acc[e]; i0 = e; }
        int i1 = -1; float l1 = -1e30f;
#pragma unroll
        for (int e = 0; e < 8; e++) if (e != i0 && acc[e] > l1) { l1 = acc[e]; i1 = e; }
        if (lane == 0) {
            float v0 = p[i0], v1 = p[i1];
            float rs = 1.f / (v0 + v1);
            idx2[n] = make_int2(i0, i1);
            wgt2[n] = make_float2(v0 * rs, v1 * rs);
            atomicAdd(&s_cnt[i0], 1);
            atomicAdd(&s_cnt[i1], 1);
#pragma unroll
            for (int e = 0; e < 8; e++) atomicAdd(&s_pi[e], p[e]);
        }
    }
    __syncthreads();
    if (t < 8) { atomicAdd(&piAcc[t], s_pi[t]); atomicAdd(&cntAcc[t], s_cnt[t]); }
}

// ---------------- offsets (exclusive scan of cnt) + aux loss
__global__ void finalize_router_kernel(const int* __restrict__ cnt, const float* __restrict__ pi,
                                       int* __restrict__ off, float* __restrict__ aux_out) {
    if (threadIdx.x == 0) {
        int o = 0;
        float dot = 0.f;
        for (int e = 0; e < 8; e++) {
            off[e] = o;
            o += cnt[e];
            dot += (float)cnt[e] * pi[e];
        }
        aux_out[0] = 0.01f * 8.f * dot / ((float)N_TOK * (float)N_TOK);
    }
}

// ---------------- scatter: build per-expert token/weight lists (block-aggregated cursors)
__global__ __launch_bounds__(256) void scatter_kernel(const int2* __restrict__ idx2, const float2* __restrict__ wgt2,
                                                      const int* __restrict__ off, int* __restrict__ cursor,
                                                      int* __restrict__ tok, float* __restrict__ gwArr) {
    __shared__ int lcnt[8], lbase[8];
    int t = threadIdx.x;
    if (t < 8) lcnt[t] = 0;
    __syncthreads();
    int a = blockIdx.x * 256 + t;
    int n = a >> 1, k = a & 1;
    int2 id = idx2[n];
    float2 w = wgt2[n];
    int e = k ? id.y : id.x;
    float wv = k ? w.y : w.x;
    int rank = atomicAdd(&lcnt[e], 1);
    __syncthreads();
    if (t < 8) lbase[t] = atomicAdd(&cursor[t], lcnt[t]);
    __syncthreads();
    int pos = off[e] + lbase[e] + rank;
    tok[pos] = n;
    gwArr[pos] = wv;
}

// ---------------- gather x rows -> packed bf16 xg (one wave per assignment row)
__global__ __launch_bounds__(256) void gather_kernel(const float* __restrict__ x, const int* __restrict__ tok,
                                                     unsigned short* __restrict__ xg) {
    int wid = threadIdx.x >> 6, lane = threadIdx.x & 63;
    int row = blockIdx.x * 4 + wid;
    int n = tok[row];
    const float4* src = (const float4*)(x + (size_t)n * C_DIM);
    ushort4* dst = (ushort4*)(xg + (size_t)row * C_DIM);
#pragma unroll
    for (int j = 0; j < 4; j++) {
        float4 v = src[lane + 64 * j];
        ushort4 o;
        o.x = f2bf(v.x); o.y = f2bf(v.y); o.z = f2bf(v.z); o.w = f2bf(v.w);
        dst[lane + 64 * j] = o;
    }
}

// ---------------- grouped GEMM, 256x256 tile, BK=64, 8 waves (2Mx4N), double-buffered LDS,
// T3 "minimum 2-phase": prefetch-next issued BEFORE compute, ONE barrier per K-step.
// B stored transposed: Bt[out-col][k]. XOR swizzle (row&7)<<4 on LDS bytes (inverse-swizzled
// global SOURCE + swizzled READ; global_load_lds writes linearly).
// EPI=0: hs[row][n0+c] = bf16(silu(acc));  EPI=1: atomicAdd(out[tok*C + c], gw*acc)
template <int EPI>
__global__ __launch_bounds__(512, 2) void moe_gemm_kernel(
    const unsigned short* __restrict__ A, int ldA,
    const unsigned short* __restrict__ Bt, int ldB, int bRowOff, int bColOff, int nBrows,
    int K, int Ncols,
    const int* __restrict__ cnt, const int* __restrict__ off,
    const int* __restrict__ tok, const float* __restrict__ gwArr,
    unsigned short* __restrict__ hs, int ldH,
    float* __restrict__ out) {
    __shared__ unsigned short As[2][256 * 64];
    __shared__ unsigned short Bs[2][256 * 64];
    int e = blockIdx.z;
    int M = cnt[e];
    int m0 = blockIdx.x * 256;
    if (m0 >= M) return;
    int baseRow = off[e];
    int n0 = blockIdx.y * 256;
    int t = threadIdx.x;
    int lane = t & 63;
    int wid = t >> 6;
    int wm = (wid >> 2) * 128;   // 2 warp-rows of 128
    int wn = (wid & 3) * 64;     // 4 warp-cols of 64

    f32x4 acc[8][4];
#pragma unroll
    for (int i = 0; i < 8; i++)
#pragma unroll
        for (int j = 0; j < 4; j++) acc[i][j] = (f32x4)0.f;

    const unsigned short* Bex = Bt + (size_t)e * (size_t)(C_DIM * H_DIM);

    auto STAGE = [&](int buf, int k0) {
#pragma unroll
        for (int i = 0; i < 4; i++) {               // A tile: 256 rows x 64 k, 2048 chunks
            int c = i * 512 + t;
            int row = c >> 3;
            int sb = ((c & 7) << 4) ^ ((row & 7) << 4);
            int colE = k0 + (sb >> 1);
            int rg = m0 + row; if (rg > M - 1) rg = M - 1;
            const unsigned short* src = A + (size_t)(baseRow + rg) * ldA + colE;
            unsigned short* dst = &As[buf][(size_t)(c & ~63) * 8];
            GLDS16(src, dst);
        }
#pragma unroll
        for (int i = 0; i < 4; i++) {               // B tile: 256 out-cols x 64 k
            int c = i * 512 + t;
            int row = c >> 3;
            int sb = ((c & 7) << 4) ^ ((row & 7) << 4);
            int colE = bColOff + k0 + (sb >> 1);
            int rowB = bRowOff + n0 + row; if (rowB > nBrows - 1) rowB = nBrows - 1;
            const unsigned short* src = Bex + (size_t)rowB * ldB + colE;
            unsigned short* dst = &Bs[buf][(size_t)(c & ~63) * 8];
            GLDS16(src, dst);
        }
    };

    int nt = K >> 6;
    STAGE(0, 0);
    __syncthreads();
    int cur = 0;
    for (int it = 0; it < nt; ++it) {
        if (it + 1 < nt) STAGE(cur ^ 1, (it + 1) << 6);
        const unsigned short* Ab = &As[cur][0];
        const unsigned short* Bb = &Bs[cur][0];
#pragma unroll
        for (int kk = 0; kk < 2; kk++) {
            short8 a[8], b[4];
#pragma unroll
            for (int m = 0; m < 8; m++) {
                int row = wm + m * 16 + (lane & 15);
                int cb = (kk * 64 + ((lane >> 4) << 4)) ^ ((row & 7) << 4);
                a[m] = *(const short8*)&Ab[row * 64 + (cb >> 1)];
            }
#pragma unroll
            for (int n = 0; n < 4; n++) {
                int row = wn + n * 16 + (lane & 15);
                int cb = (kk * 64 + ((lane >> 4) << 4)) ^ ((row & 7) << 4);
                b[n] = *(const short8*)&Bb[row * 64 + (cb >> 1)];
            }
            __builtin_amdgcn_s_setprio(1);
#pragma unroll
            for (int m = 0; m < 8; m++)
#pragma unroll
                for (int n = 0; n < 4; n++)
                    acc[m][n] = __builtin_amdgcn_mfma_f32_16x16x32_bf16(a[m], b[n], acc[m][n], 0, 0, 0);
            __builtin_amdgcn_s_setprio(0);
        }
        __syncthreads();   // drains vmcnt (prefetch done) + all waves finished reading buf[cur]
        cur ^= 1;
    }

    int gRow = (lane >> 4) * 4;
    int cLane = lane & 15;
#pragma unroll
    for (int m = 0; m < 8; m++) {
#pragma unroll
        for (int j = 0; j < 4; j++) {
            int r = m0 + wm + m * 16 + gRow + j;
            if (r < M) {
                if (EPI == 0) {
#pragma unroll
                    for (int n = 0; n < 4; n++) {
                        int c = n0 + wn + n * 16 + cLane;
                        if (c < Ncols) {
                            float v = acc[m][n][j];
                            float sv = v / (1.f + __expf(-v));
                            hs[(size_t)(baseRow + r) * ldH + c] = f2bf(sv);
                        }
                    }
                } else {
                    int token = tok[baseRow + r];
                    float w = gwArr[baseRow + r];
#pragma unroll
                    for (int n = 0; n < 4; n++) {
                        int c = n0 + wn + n * 16 + cLane;
                        if (c < Ncols) atomicAdd(&out[(size_t)token * C_DIM + c], w * acc[m][n][j]);
                    }
                }
            }
        }
    }
}

extern "C" void kernel_launch(void* const* d_in, const int* in_sizes, int n_in,
                              void* d_out, int out_size, void* d_ws, size_t ws_size,
                              hipStream_t stream) {
    const float* x = (const float*)d_in[0];
    const float* W1 = (const float*)d_in[1];
    const float* W2 = (const float*)d_in[2];
    const float* Wr = (const float*)d_in[3];
    float* out = (float*)d_out;

    char* p = (char*)d_ws;
    auto alloc = [&](size_t bytes) {
        char* r = p;
        p += (bytes + 255) & ~(size_t)255;
        return r;
    };
    float* pi = (float*)alloc(8 * sizeof(float));
    int* cntA = (int*)alloc(8 * sizeof(int));
    int* cursor = (int*)alloc(8 * sizeof(int));
    int* offA = (int*)alloc(8 * sizeof(int));
    int2* idx2 = (int2*)alloc((size_t)N_TOK * sizeof(int2));
    float2* wgt2 = (float2*)alloc((size_t)N_TOK * sizeof(float2));
    int* tok = (int*)alloc((size_t)N_ASSIGN * sizeof(int));
    float* gwA = (float*)alloc((size_t)N_ASSIGN * sizeof(float));
    unsigned short* W1bT = (unsigned short*)alloc((size_t)N_EXP * C_DIM * H_DIM * 2);
    unsigned short* W2bT = (unsigned short*)alloc((size_t)N_EXP * C_DIM * H_DIM * 2);
    unsigned short* xg = (unsigned short*)alloc((size_t)N_ASSIGN * C_DIM * 2);
    size_t used = (size_t)(p - (char*)d_ws);
    size_t remain = ws_size > used ? ws_size - used : 0;
    int HC = H_DIM;
    while (HC > 384 && (size_t)N_ASSIGN * HC * 2 > remain) HC >>= 1;
    unsigned short* hs = (unsigned short*)p;

    hipMemsetAsync(d_ws, 0, 1024, stream);                                      // pi, cnt, cursor, off
    hipMemsetAsync(d_out, 0, (size_t)N_TOK * C_DIM * sizeof(float), stream);    // accumulated output

    dim3 tb(32, 32, 1);
    transpose_bf16_kernel<<<dim3(H_DIM / 32, C_DIM / 32, N_EXP), tb, 0, stream>>>(W1, W1bT, C_DIM, H_DIM);
    transpose_bf16_kernel<<<dim3(C_DIM / 32, H_DIM / 32, N_EXP), tb, 0, stream>>>(W2, W2bT, H_DIM, C_DIM);

    router_kernel<<<256, 256, 0, stream>>>(x, Wr, idx2, wgt2, pi, cntA);
    finalize_router_kernel<<<1, 64, 0, stream>>>(cntA, pi, offA, out + (size_t)N_TOK * C_DIM);
    scatter_kernel<<<N_ASSIGN / 256, 256, 0, stream>>>(idx2, wgt2, offA, cursor, tok, gwA);
    gather_kernel<<<N_ASSIGN / 4, 256, 0, stream>>>(x, tok, xg);

    int nChunks = H_DIM / HC;
    for (int ci = 0; ci < nChunks; ++ci) {
        int h0 = ci * HC;
        // GEMM1: [M_e x C] @ W1^T[H x C] -> silu -> hs[. x HC]
        moe_gemm_kernel<0><<<dim3(32, (HC + 255) / 256, N_EXP), 512, 0, stream>>>(
            xg, C_DIM, W1bT, C_DIM, h0, 0, H_DIM, C_DIM, HC, cntA, offA, tok, gwA, hs, HC, out);
        // GEMM2: [M_e x HC] @ W2^T[C x H] -> scaled atomic scatter into out
        moe_gemm_kernel<1><<<dim3(32, 4, N_EXP), 512, 0, stream>>>(
            hs, HC, W2bT, H_DIM, 0, h0, C_DIM, HC, C_DIM, cntA, offA, tok, gwA, hs, HC, out);
    }
}

// Round 3
// 528.637 us; speedup vs baseline: 2.6057x; 2.6057x over previous
//
#include <hip/hip_runtime.h>
#include <stdint.h>

#define N_TOK 8192
#define C_DIM 1024
#define H_DIM 3072
#define N_EXP 8
#define N_ASSIGN (N_TOK * 2)

typedef __attribute__((ext_vector_type(8))) short short8;
typedef __attribute__((ext_vector_type(4))) float f32x4;

__device__ __forceinline__ unsigned short f2bf(float f) {
    union { float f; uint32_t u; } v; v.f = f;
    uint32_t r = (v.u + 0x7FFFu + ((v.u >> 16) & 1u)) >> 16;
    return (unsigned short)r;
}

#define GLDS16(SRC, DST) __builtin_amdgcn_global_load_lds( \
    (const __attribute__((address_space(1))) void*)(SRC),  \
    (__attribute__((address_space(3))) void*)(DST), 16, 0, 0)

// ---------------- transpose + fp32->bf16 convert: out[col][row] = in[row][col], per expert (grid.z)
__global__ void transpose_bf16_kernel(const float* __restrict__ in, unsigned short* __restrict__ out,
                                      int rows, int cols) {
    __shared__ float tile[32][33];
    int e = blockIdx.z;
    const float* ip = in + (size_t)e * rows * cols;
    unsigned short* op = out + (size_t)e * rows * cols;
    int col0 = blockIdx.x * 32;
    int row0 = blockIdx.y * 32;
    int tx = threadIdx.x, ty = threadIdx.y;
    tile[ty][tx] = ip[(size_t)(row0 + ty) * cols + col0 + tx];
    __syncthreads();
    op[(size_t)(col0 + ty) * rows + row0 + tx] = f2bf(tile[tx][ty]);
}

// ---------------- router: logits = x @ Wr, softmax, top-2 (lowest-index ties), renorm; pi/cnt stats
__global__ __launch_bounds__(256) void router_kernel(const float* __restrict__ x, const float* __restrict__ Wr,
                                                     int2* __restrict__ idx2, float2* __restrict__ wgt2,
                                                     float* __restrict__ piAcc, int* __restrict__ cntAcc) {
    __shared__ float s_pi[8];
    __shared__ int s_cnt[8];
    int t = threadIdx.x;
    if (t < 8) { s_pi[t] = 0.f; s_cnt[t] = 0; }
    __syncthreads();
    int lane = t & 63;
    int wid = t >> 6;
    int gwv = blockIdx.x * 4 + wid;
    int nw = gridDim.x * 4;
    for (int n = gwv; n < N_TOK; n += nw) {
        float acc[8];
#pragma unroll
        for (int e = 0; e < 8; e++) acc[e] = 0.f;
        const float* xr = x + (size_t)n * C_DIM;
#pragma unroll
        for (int j = 0; j < 16; j++) {
            int k = lane + 64 * j;
            float xv = xr[k];
            const float4* wr4 = (const float4*)(Wr + (size_t)k * 8);
            float4 a = wr4[0], b = wr4[1];
            acc[0] += xv * a.x; acc[1] += xv * a.y; acc[2] += xv * a.z; acc[3] += xv * a.w;
            acc[4] += xv * b.x; acc[5] += xv * b.y; acc[6] += xv * b.z; acc[7] += xv * b.w;
        }
#pragma unroll
        for (int off = 1; off < 64; off <<= 1) {
#pragma unroll
            for (int e = 0; e < 8; e++) acc[e] += __shfl_xor(acc[e], off, 64);
        }
        float m = acc[0];
#pragma unroll
        for (int e = 1; e < 8; e++) m = fmaxf(m, acc[e]);
        float p[8]; float s = 0.f;
#pragma unroll
        for (int e = 0; e < 8; e++) { p[e] = __expf(acc[e] - m); s += p[e]; }
        float inv = 1.f / s;
#pragma unroll
        for (int e = 0; e < 8; e++) p[e] *= inv;
        int i0 = 0; float l0 = acc[0];
#pragma unroll
        for (int e = 1; e < 8; e++) if (acc[e] > l0) { l0 = acc[e]; i0 = e; }
        int i1 = -1; float l1 = -1e30f;
#pragma unroll
        for (int e = 0; e < 8; e++) if (e != i0 && acc[e] > l1) { l1 = acc[e]; i1 = e; }
        if (lane == 0) {
            float v0 = p[i0], v1 = p[i1];
            float rs = 1.f / (v0 + v1);
            idx2[n] = make_int2(i0, i1);
            wgt2[n] = make_float2(v0 * rs, v1 * rs);
            atomicAdd(&s_cnt[i0], 1);
            atomicAdd(&s_cnt[i1], 1);
#pragma unroll
            for (int e = 0; e < 8; e++) atomicAdd(&s_pi[e], p[e]);
        }
    }
    __syncthreads();
    if (t < 8) { atomicAdd(&piAcc[t], s_pi[t]); atomicAdd(&cntAcc[t], s_cnt[t]); }
}

// ---------------- offsets (exclusive scan of cnt) + aux loss
__global__ void finalize_router_kernel(const int* __restrict__ cnt, const float* __restrict__ pi,
                                       int* __restrict__ off, float* __restrict__ aux_out) {
    if (threadIdx.x == 0) {
        int o = 0;
        float dot = 0.f;
        for (int e = 0; e < 8; e++) {
            off[e] = o;
            o += cnt[e];
            dot += (float)cnt[e] * pi[e];
        }
        aux_out[0] = 0.01f * 8.f * dot / ((float)N_TOK * (float)N_TOK);
    }
}

// ---------------- scatter: build per-expert token/weight lists (block-aggregated cursors)
__global__ __launch_bounds__(256) void scatter_kernel(const int2* __restrict__ idx2, const float2* __restrict__ wgt2,
                                                      const int* __restrict__ off, int* __restrict__ cursor,
                                                      int* __restrict__ tok, float* __restrict__ gwArr) {
    __shared__ int lcnt[8], lbase[8];
    int t = threadIdx.x;
    if (t < 8) lcnt[t] = 0;
    __syncthreads();
    int a = blockIdx.x * 256 + t;
    int n = a >> 1, k = a & 1;
    int2 id = idx2[n];
    float2 w = wgt2[n];
    int e = k ? id.y : id.x;
    float wv = k ? w.y : w.x;
    int rank = atomicAdd(&lcnt[e], 1);
    __syncthreads();
    if (t < 8) lbase[t] = atomicAdd(&cursor[t], lcnt[t]);
    __syncthreads();
    int pos = off[e] + lbase[e] + rank;
    tok[pos] = n;
    gwArr[pos] = wv;
}

// ---------------- gather x rows -> packed bf16 xg (one wave per assignment row)
__global__ __launch_bounds__(256) void gather_kernel(const float* __restrict__ x, const int* __restrict__ tok,
                                                     unsigned short* __restrict__ xg) {
    int wid = threadIdx.x >> 6, lane = threadIdx.x & 63;
    int row = blockIdx.x * 4 + wid;
    int n = tok[row];
    const float4* src = (const float4*)(x + (size_t)n * C_DIM);
    ushort4* dst = (ushort4*)(xg + (size_t)row * C_DIM);
#pragma unroll
    for (int j = 0; j < 4; j++) {
        float4 v = src[lane + 64 * j];
        ushort4 o;
        o.x = f2bf(v.x); o.y = f2bf(v.y); o.z = f2bf(v.z); o.w = f2bf(v.w);
        dst[lane + 64 * j] = o;
    }
}

// ---------------- grouped GEMM, 256x256 tile, BK=32, 8 waves (2Mx4N)
// 4-buffer LDS ring, never-drain pipeline: stage tile t+3 while computing tile t
// (12 gload_lds in flight per wave). One raw s_barrier per iteration; counted
// s_waitcnt vmcnt(8) (peeled tail: 4, 0). Expert-per-XCD: wg&7 = expert, so each
// XCD's L2 keeps one expert's A-panel + B-panels hot.
// LDS layout: row-pairs in 128B lines, chunk ^= (line&7) swizzle applied to
// SOURCE and READ (gload_lds dst stays linear).
// EPI=0: hs = bf16(silu(acc)); EPI=1: atomicAdd(out[tok*C+c], gw*acc)
#define GEMM_BODY(WAITSTR, DOSTAGE)                                                 \
    {                                                                               \
        __builtin_amdgcn_sched_barrier(0);                                          \
        asm volatile(WAITSTR ::: "memory");                                         \
        __builtin_amdgcn_sched_barrier(0);                                          \
        __builtin_amdgcn_s_barrier();                                               \
        __builtin_amdgcn_sched_barrier(0);                                          \
        int bb = (t & 3) * 16384;                                                   \
        short8 a[8], b[4];                                                          \
        _Pragma("unroll")                                                           \
        for (int m = 0; m < 8; m++) a[m] = *(const short8*)&smem[bb + offA[m]];     \
        _Pragma("unroll")                                                           \
        for (int n = 0; n < 4; n++) b[n] = *(const short8*)&smem[bb + offB[n]];     \
        if (DOSTAGE) STAGE((t + 3) & 3);                                            \
        __builtin_amdgcn_s_setprio(1);                                              \
        _Pragma("unroll")                                                           \
        for (int m = 0; m < 8; m++)                                                 \
            _Pragma("unroll")                                                       \
            for (int n = 0; n < 4; n++)                                             \
                acc[m][n] = __builtin_amdgcn_mfma_f32_16x16x32_bf16(a[m], b[n], acc[m][n], 0, 0, 0); \
        __builtin_amdgcn_s_setprio(0);                                              \
    }

template <int EPI>
__global__ __launch_bounds__(512, 2) void moe_gemm_kernel(
    const unsigned short* __restrict__ A, int ldA,
    const unsigned short* __restrict__ Bt, int ldB, int bRowOff, int bColOff,
    int K,
    const int* __restrict__ cnt, const int* __restrict__ off,
    const int* __restrict__ tok, const float* __restrict__ gwArr,
    unsigned short* __restrict__ hs, int ldH,
    float* __restrict__ out) {
    __shared__ unsigned short smem[65536];   // 4 bufs x (A 8192 + B 8192 shorts) = 128 KiB
    const int MB = 16;                        // m-blocks per panel (covers M up to 4096)
    int wg = blockIdx.x;
    int e = wg & 7;                           // expert == XCD (wg%8 dispatch round-robin)
    int loc = wg >> 3;
    int y = loc / MB;
    int mblk = loc - y * MB;
    int M = cnt[e];
    int m0 = mblk * 256;
    if (m0 >= M) return;
    int baseRow = off[e];
    int n0 = y * 256;
    int tid = threadIdx.x;
    int lane = tid & 63;
    int wid = tid >> 6;
    int wm = (wid >> 2) * 128;
    int wn = (wid & 3) * 64;

    f32x4 acc[8][4];
#pragma unroll
    for (int i = 0; i < 8; i++)
#pragma unroll
        for (int j = 0; j < 4; j++) acc[i][j] = (f32x4)0.f;

    const unsigned short* Bex = Bt + (size_t)e * (size_t)(C_DIM * H_DIM);

    // stage pointers: per thread 2 A-chunks + 2 B-chunks (16B each) per tile
    const unsigned short* srcA[2];
    const unsigned short* srcB[2];
    int ldsOff[2];
#pragma unroll
    for (int i = 0; i < 2; i++) {
        int c = i * 512 + tid;
        int rl = c >> 3, cl = c & 7;
        int cls = cl ^ (rl & 7);              // inverse swizzle on source
        int row = (rl << 1) | (cls >> 2);
        int kc = cls & 3;
        int rg = m0 + row; if (rg > M - 1) rg = M - 1;
        srcA[i] = A + (size_t)(baseRow + rg) * ldA + kc * 8;
        srcB[i] = Bex + (size_t)(bRowOff + n0 + row) * ldB + bColOff + kc * 8;
        ldsOff[i] = (c & ~63) * 8;            // shorts; wave-uniform base, lane*16B implicit
    }
    auto STAGE = [&](int buf) {
        int bb = buf * 16384;
#pragma unroll
        for (int i = 0; i < 2; i++) {
            GLDS16(srcA[i], &smem[bb + ldsOff[i]]);
            GLDS16(srcB[i], &smem[bb + 8192 + ldsOff[i]]);
            srcA[i] += 32; srcB[i] += 32;     // advance k by BK=32
        }
    };

    // swizzled read offsets (shorts): row r, k-quarter kq -> line r>>1, chunk ^ (line&7)
    int kq = lane >> 4;
    int rsub = lane & 15;
    int offA[8], offB[4];
#pragma unroll
    for (int m = 0; m < 8; m++) {
        int r = wm + m * 16 + rsub;
        int rl = r >> 1;
        int cls = (((r & 1) << 2) | kq) ^ (rl & 7);
        offA[m] = rl * 64 + cls * 8;
    }
#pragma unroll
    for (int n = 0; n < 4; n++) {
        int r = wn + n * 16 + rsub;
        int rl = r >> 1;
        int cls = (((r & 1) << 2) | kq) ^ (rl & 7);
        offB[n] = 8192 + rl * 64 + cls * 8;
    }

    int nt = K >> 5;
    STAGE(0); STAGE(1); STAGE(2);             // 12 loads in flight
    int t = 0;
#pragma unroll 1
    for (; t < nt - 2; ++t) GEMM_BODY("s_waitcnt vmcnt(8)", (t + 3 < nt))
    GEMM_BODY("s_waitcnt vmcnt(4)", false); ++t;
    GEMM_BODY("s_waitcnt vmcnt(0)", false);

    int gRow = (lane >> 4) * 4;
    int cLane = lane & 15;
#pragma unroll
    for (int m = 0; m < 8; m++) {
#pragma unroll
        for (int j = 0; j < 4; j++) {
            int r = m0 + wm + m * 16 + gRow + j;
            if (r < M) {
                if (EPI == 0) {
#pragma unroll
                    for (int n = 0; n < 4; n++) {
                        int c = n0 + wn + n * 16 + cLane;
                        float v = acc[m][n][j];
                        float sv = v / (1.f + __expf(-v));
                        hs[(size_t)(baseRow + r) * ldH + c] = f2bf(sv);
                    }
                } else {
                    int token = tok[baseRow + r];
                    float w = gwArr[baseRow + r];
#pragma unroll
                    for (int n = 0; n < 4; n++) {
                        int c = n0 + wn + n * 16 + cLane;
                        atomicAdd(&out[(size_t)token * C_DIM + c], w * acc[m][n][j]);
                    }
                }
            }
        }
    }
}

extern "C" void kernel_launch(void* const* d_in, const int* in_sizes, int n_in,
                              void* d_out, int out_size, void* d_ws, size_t ws_size,
                              hipStream_t stream) {
    const float* x = (const float*)d_in[0];
    const float* W1 = (const float*)d_in[1];
    const float* W2 = (const float*)d_in[2];
    const float* Wr = (const float*)d_in[3];
    float* out = (float*)d_out;

    char* p = (char*)d_ws;
    auto alloc = [&](size_t bytes) {
        char* r = p;
        p += (bytes + 255) & ~(size_t)255;
        return r;
    };
    float* pi = (float*)alloc(8 * sizeof(float));
    int* cntA = (int*)alloc(8 * sizeof(int));
    int* cursor = (int*)alloc(8 * sizeof(int));
    int* offA = (int*)alloc(8 * sizeof(int));
    int2* idx2 = (int2*)alloc((size_t)N_TOK * sizeof(int2));
    float2* wgt2 = (float2*)alloc((size_t)N_TOK * sizeof(float2));
    int* tok = (int*)alloc((size_t)N_ASSIGN * sizeof(int));
    float* gwA = (float*)alloc((size_t)N_ASSIGN * sizeof(float));
    unsigned short* W1bT = (unsigned short*)alloc((size_t)N_EXP * C_DIM * H_DIM * 2);
    unsigned short* W2bT = (unsigned short*)alloc((size_t)N_EXP * C_DIM * H_DIM * 2);
    unsigned short* xg = (unsigned short*)alloc((size_t)N_ASSIGN * C_DIM * 2);
    size_t used = (size_t)(p - (char*)d_ws);
    size_t remain = ws_size > used ? ws_size - used : 0;
    int HC = H_DIM;
    while (HC > 384 && (size_t)N_ASSIGN * HC * 2 > remain) HC >>= 1;
    unsigned short* hs = (unsigned short*)p;

    hipMemsetAsync(d_ws, 0, 1024, stream);                                      // pi, cnt, cursor, off
    hipMemsetAsync(d_out, 0, (size_t)N_TOK * C_DIM * sizeof(float), stream);    // accumulated output

    dim3 tb(32, 32, 1);
    transpose_bf16_kernel<<<dim3(H_DIM / 32, C_DIM / 32, N_EXP), tb, 0, stream>>>(W1, W1bT, C_DIM, H_DIM);
    transpose_bf16_kernel<<<dim3(C_DIM / 32, H_DIM / 32, N_EXP), tb, 0, stream>>>(W2, W2bT, H_DIM, C_DIM);

    router_kernel<<<256, 256, 0, stream>>>(x, Wr, idx2, wgt2, pi, cntA);
    finalize_router_kernel<<<1, 64, 0, stream>>>(cntA, pi, offA, out + (size_t)N_TOK * C_DIM);
    scatter_kernel<<<N_ASSIGN / 256, 256, 0, stream>>>(idx2, wgt2, offA, cursor, tok, gwA);
    gather_kernel<<<N_ASSIGN / 4, 256, 0, stream>>>(x, tok, xg);

    int nChunks = H_DIM / HC;
    for (int ci = 0; ci < nChunks; ++ci) {
        int h0 = ci * HC;
        int ny1 = HC / 256;
        // GEMM1: [M_e x C] @ W1^T[H x C] -> silu -> hs[. x HC]
        moe_gemm_kernel<0><<<dim3(8 * ny1 * 16, 1, 1), 512, 0, stream>>>(
            xg, C_DIM, W1bT, C_DIM, h0, 0, C_DIM, cntA, offA, tok, gwA, hs, HC, out);
        // GEMM2: [M_e x HC] @ W2^T[C x H] -> scaled atomic scatter into out
        moe_gemm_kernel<1><<<dim3(8 * 4 * 16, 1, 1), 512, 0, stream>>>(
            hs, HC, W2bT, H_DIM, 0, h0, HC, cntA, offA, tok, gwA, hs, HC, out);
    }
}